// Round 1
// baseline (2439.123 us; speedup 1.0000x reference)
//
#include <hip/hip_runtime.h>
#include <hip/hip_bf16.h>

// Problem constants (fixed in the reference file)
#define NNZ 2000000
#define D 64
#define N_COLS 100000

// Stage 2: scatter-add values into pooled[n_cols][64].
// One thread per float4 of values: tid in [0, nnz*16).
__global__ void scatter_add_kernel(const float4* __restrict__ vals,
                                   const int* __restrict__ seg,
                                   float* __restrict__ pooled,
                                   long long total_vec) {
    long long tid = (long long)blockIdx.x * blockDim.x + threadIdx.x;
    if (tid >= total_vec) return;
    int i = (int)(tid >> 4);   // nnz row
    int q = (int)(tid & 15);   // float4 slot within row (0..15)
    float4 v = vals[tid];
    int c = seg[i];
    float* p = pooled + (long long)c * D + q * 4;
    atomicAdd(p + 0, v.x);
    atomicAdd(p + 1, v.y);
    atomicAdd(p + 2, v.z);
    atomicAdd(p + 3, v.w);
}

// Stage 3: gather pooled rows back out.
__global__ void gather_kernel(const float* __restrict__ pooled,
                              const int* __restrict__ seg,
                              float4* __restrict__ out,
                              long long total_vec) {
    long long tid = (long long)blockIdx.x * blockDim.x + threadIdx.x;
    if (tid >= total_vec) return;
    int i = (int)(tid >> 4);
    int q = (int)(tid & 15);
    int c = seg[i];
    const float4* row = (const float4*)(pooled + (long long)c * D);
    out[tid] = row[q];
}

extern "C" void kernel_launch(void* const* d_in, const int* in_sizes, int n_in,
                              void* d_out, int out_size, void* d_ws, size_t ws_size,
                              hipStream_t stream) {
    const float* values = (const float*)d_in[0];     // [NNZ, 64] f32
    const int* indices  = (const int*)d_in[1];       // [2, NNZ] i32
    const int* seg      = indices + NNZ;             // indices[1]
    float* out          = (float*)d_out;             // [NNZ, 64] f32
    float* pooled       = (float*)d_ws;              // [N_COLS, 64] f32 scratch

    // Stage 1: zero the pooled accumulator (d_ws is re-poisoned every call).
    size_t pooled_bytes = (size_t)N_COLS * D * sizeof(float);
    hipMemsetAsync(pooled, 0, pooled_bytes, stream);

    const long long total_vec = (long long)NNZ * (D / 4);  // 32M float4 slots
    const int block = 256;
    const int grid = (int)((total_vec + block - 1) / block);

    scatter_add_kernel<<<grid, block, 0, stream>>>(
        (const float4*)values, seg, pooled, total_vec);

    gather_kernel<<<grid, block, 0, stream>>>(
        pooled, seg, (float4*)out, total_vec);
}